// Round 9
// baseline (50546.899 us; speedup 1.0000x reference)
//
#include <hip/hip_runtime.h>
#include <math.h>

#define NH 16
#define HD 64
#define DM 1024
#define DMLP 4096
#define NB 8
#define JT 17
#define LN_EPS 1e-5

__global__ __launch_bounds__(256) void sentinel_kernel(float* o, float v){
  o[threadIdx.x] = v;
}

// ---------------- scalar elementwise ----------------
__global__ __launch_bounds__(256) void dbcast(const float* __restrict__ src, float* __restrict__ dst){
  size_t id = (size_t)blockIdx.x*256 + threadIdx.x;
  if(id < (size_t)NB*256*DM) dst[id] = src[id % ((size_t)256*DM)];
}

__global__ __launch_bounds__(256) void dcopy(const float* __restrict__ src, float* __restrict__ dst, size_t n){
  size_t id = (size_t)blockIdx.x*256 + threadIdx.x;
  if(id < n) dst[id] = src[id];
}

// pos *= la[l]; x[:, JT+p, :] += pos
__global__ __launch_bounds__(256) void dposadd(float* __restrict__ x, float* __restrict__ pos,
    const float* __restrict__ la, int l, int n, int P){
  size_t id = (size_t)blockIdx.x*256 + threadIdx.x;
  size_t tot = (size_t)NB*P*DM;
  if(id >= tot) return;
  int c = (int)(id % DM); size_t rt = id / DM;
  int p = (int)(rt % P); int b = (int)(rt / P);
  double lav = (double)la[l];
  size_t pi = ((size_t)b*P + p)*DM + c;
  double pv = (double)pos[pi] * lav;
  pos[pi] = (float)pv;
  size_t xi = ((size_t)b*n + JT + p)*DM + c;
  x[xi] = (float)((double)x[xi] + pv);
}

// ---------------- LayerNorm: one thread per row, serial f64 ----------------
__global__ __launch_bounds__(64) void dln(const float* __restrict__ x,
    const float* __restrict__ g, const float* __restrict__ bb, float* __restrict__ o, int M){
  int r = blockIdx.x*64 + threadIdx.x;
  if(r >= M) return;
  const float* xr = x + (size_t)r*DM;
  double s = 0.0;
  for(int c=0;c<DM;c++) s += (double)xr[c];
  double mean = s * (1.0/DM);
  double v = 0.0;
  for(int c=0;c<DM;c++){ double d = (double)xr[c]-mean; v += d*d; }
  double inv = 1.0 / sqrt(v*(1.0/DM) + LN_EPS);
  float* orow = o + (size_t)r*DM;
  for(int c=0;c<DM;c++)
    orow[c] = (float)(((double)xr[c]-mean)*inv*(double)g[c] + (double)bb[c]);
}

// ---------------- 16x16-tile GEMM, one output element/thread, f64 acc ----------------
__global__ __launch_bounds__(256) void dgemm(const float* __restrict__ A, const float* __restrict__ Bw,
    const float* __restrict__ bias, const float* __restrict__ res,
    float* __restrict__ C, int M, int N, int K, int act){
  __shared__ float As[16][17], Bs[16][17];
  int tx = threadIdx.x & 15, ty = threadIdx.x >> 4;
  int i  = blockIdx.y*16 + ty;
  int j0 = blockIdx.x*16;
  int j  = j0 + tx;
  double acc = 0.0;
  for(int k0=0;k0<K;k0+=16){
    As[ty][tx] = (i < M) ? A[(size_t)i*K + k0 + tx] : 0.f;
    Bs[ty][tx] = Bw[(size_t)(j0 + ty)*K + k0 + tx];
    __syncthreads();
    for(int kk=0;kk<16;kk++) acc += (double)As[ty][kk] * (double)Bs[tx][kk];
    __syncthreads();
  }
  if(i < M){
    if(bias) acc += (double)bias[j];
    if(act)  acc = 0.5*acc*(1.0 + erf(acc*0.70710678118654752440));
    if(res)  acc += (double)res[(size_t)i*N + j];
    C[(size_t)i*N + j] = (float)acc;
  }
}

// ---------------- RoPE ----------------
__global__ __launch_bounds__(256) void drope(const float* __restrict__ qkv, const float* __restrict__ fc,
    float* __restrict__ Q, float* __restrict__ K, float* __restrict__ V, int n){
  int id = blockIdx.x*256 + threadIdx.x;     // NB*n*512
  if(id >= NB*n*512) return;
  int pr = id & 511; int bt = id >> 9;
  int b = bt / n, t = bt % n;
  int h = pr >> 5, d2 = pr & 31;
  const float* row = qkv + (size_t)bt*3072;
  double c = (double)fc[(t*32+d2)*2], s = (double)fc[(t*32+d2)*2+1];
  double qa = (double)row[h*HD+2*d2], qb = (double)row[h*HD+2*d2+1];
  double ka = (double)row[DM + h*HD+2*d2], kb = (double)row[DM + h*HD+2*d2+1];
  size_t base = ((size_t)(b*NH+h)*n + t)*HD + 2*d2;
  Q[base]   = (float)((qa*c - qb*s)*0.03125);
  Q[base+1] = (float)((qa*s + qb*c)*0.03125);
  K[base]   = (float)(ka*c - kb*s);
  K[base+1] = (float)(ka*s + kb*c);
  V[base]   = row[2048 + h*HD + 2*d2];
  V[base+1] = row[2048 + h*HD + 2*d2 + 1];
}

// ---------------- scores + softmax: one thread per (b,h,i), serial f64, f32 store ----------------
__global__ __launch_bounds__(64) void dscores(const float* __restrict__ Q, const float* __restrict__ K,
    float* __restrict__ attn, int n){
  int id = blockIdx.x*64 + threadIdx.x;      // NB*NH*n
  if(id >= NB*NH*n) return;
  int i = id % n; int bh = id / n;
  const float* qr = Q + ((size_t)bh*n + i)*HD;
  const float* kb = K + (size_t)bh*n*HD;
  double s[273];
  double mx = -1.0e300;
  for(int j=0;j<n;j++){
    double a = 0.0;
    const float* kr = kb + (size_t)j*HD;
    for(int d=0;d<HD;d++) a += (double)qr[d]*(double)kr[d];
    s[j] = a; if(a > mx) mx = a;
  }
  double sum = 0.0;
  for(int j=0;j<n;j++){ s[j] = exp(s[j]-mx); sum += s[j]; }
  double inv = 1.0/sum;
  float* arow = attn + ((size_t)bh*n + i)*n;
  for(int j=0;j<n;j++) arow[j] = (float)(s[j]*inv);
}

// ---------------- PV ----------------
__global__ __launch_bounds__(256) void dpv(const float* __restrict__ attn, const float* __restrict__ V,
    float* __restrict__ O, int n){
  size_t id = (size_t)blockIdx.x*256 + threadIdx.x;  // NB*NH*n*64
  if(id >= (size_t)NB*NH*n*HD) return;
  int d = (int)(id & 63); size_t rest = id >> 6;
  int i = (int)(rest % n); int bh = (int)(rest / n);
  int b = bh >> 4, h = bh & 15;
  const float* ar = attn + ((size_t)bh*n + i)*n;
  const float* vb = V + ((size_t)bh*n)*HD + d;
  double acc = 0.0;
  for(int j=0;j<n;j++) acc += (double)ar[j] * (double)vb[(size_t)j*HD];
  O[((size_t)(b*n + i))*DM + h*HD + d] = (float)acc;
}

// ---------------- human scores: f32 from STORED attn, np reduction order ----------------
// tok_attn[i] = (serial-sum_h attn_f32) * (1/16 f32); human = serial-sum_i tok_attn (f32)
// (numpy reduces non-contiguous axes serially, vectorized across the last axis)
__global__ __launch_bounds__(256) void dhuman32(const float* __restrict__ attn, float* __restrict__ hum32, int n){
  int id = blockIdx.x*256 + threadIdx.x;
  int P = n - JT;
  if(id >= NB*P) return;
  int b = id / P, p = id % P;
  float s = 0.f;
  for(int i=0;i<JT;i++){
    float th = 0.f;
    for(int h=0;h<NH;h++) th += attn[(((size_t)(b*NH+h))*n + i)*n + JT + p];
    th *= 0.0625f;
    s += th;
  }
  hum32[b*256 + p] = s;
}

// ---------------- top-k: rank order (descending value, ties->lower index) ----------------
__global__ __launch_bounds__(64) void dselect32(const float* __restrict__ hum, int* __restrict__ sel, int P, int k){
  int b = threadIdx.x;
  if(b >= NB) return;
  const float* h = hum + b*256;
  bool taken[256];
  for(int p=0;p<P;p++) taken[p] = false;
  for(int r=0;r<k;r++){
    float best = -3.0e38f; int bi = 0;
    for(int p=0;p<P;p++)
      if(!taken[p] && h[p] > best){ best = h[p]; bi = p; }
    sel[b*192 + r] = bi; taken[bi] = true;
  }
}

// ---------------- gather ----------------
__global__ __launch_bounds__(256) void dgather(const float* __restrict__ xin, const float* __restrict__ pin,
    const int* __restrict__ sel, float* __restrict__ xout, float* __restrict__ pout, int n_old, int k){
  int n_new = JT + k;
  size_t id = (size_t)blockIdx.x*256 + threadIdx.x;
  size_t tot = (size_t)NB*n_new*DM;
  if(id >= tot) return;
  int c = (int)(id % DM); size_t rt = id / DM;
  int t = (int)(rt % n_new); int b = (int)(rt / n_new);
  int src = (t < JT) ? t : (JT + sel[b*192 + (t-JT)]);
  xout[((size_t)b*n_new + t)*DM + c] = xin[((size_t)b*n_old + src)*DM + c];
  if(t >= JT)
    pout[((size_t)b*k + (t-JT))*DM + c] = pin[((size_t)b*(n_old-JT) + (src-JT))*DM + c];
}

// ---------------- host ----------------
extern "C" void kernel_launch(void* const* d_in, const int* in_sizes, int n_in,
                              void* d_out, int out_size, void* d_ws, size_t ws_size,
                              hipStream_t stream){
  float* out = (float*)d_out;

  const size_t NEED = 26560512ull * 4ull;    // 106.2 MB (ws proven >= 111 MB earlier)
  if(ws_size < NEED){
    sentinel_kernel<<<1,256,0,stream>>>(out, 1000000.0f);
    return;
  }

  const float* x_in  = (const float*)d_in[0];
  const float* freqs = (const float*)d_in[1];
  const float* la    = (const float*)d_in[2];
  const float* pos_in= (const float*)d_in[3];
  const float* ln1g  = (const float*)d_in[4];
  const float* ln1b  = (const float*)d_in[5];
  const float* wqkv  = (const float*)d_in[6];
  const float* wout  = (const float*)d_in[7];
  const float* bout  = (const float*)d_in[8];
  const float* ln2g  = (const float*)d_in[9];
  const float* ln2b  = (const float*)d_in[10];
  const float* w1    = (const float*)d_in[11];
  const float* b1    = (const float*)d_in[12];
  const float* w2    = (const float*)d_in[13];
  const float* b2    = (const float*)d_in[14];

  float* w = (float*)d_ws;
  float* XA = w;  w += 2236416;            // 8*273*1024
  float* XB = w;  w += 2236416;
  float* Hb = w;  w += 2236416;
  float* QKV= w;                            // 8*273*3072; FF spans QKV+Qb (dead in FFN phase)
  float* FF = QKV;
  float* HUM32 = QKV;                       // alias: live only during prune (QKV dead there)
                  w += 6709248;
  float* Qb = w;  w += 2236416;
  float* Kb = w;  w += 2236416;
  float* Vb = w;  w += 2236416;
  float* Ob = w;  w += 2236416;
  float* PA = w;  w += 2097152;            // 8*256*1024
  float* PB = w;  w += 2097152;
  int*   SEL = (int*)w; w += 2048;         // stride 192 per batch

  hipMemcpyAsync(XA, x_in, (size_t)NB*273*DM*sizeof(float), hipMemcpyDeviceToDevice, stream);
  dbcast<<<8192,256,0,stream>>>(pos_in, PA);

  float* xc = XA; float* xa = XB;
  float* pc = PA; float* pa = PB;
  int n = 273, P = 256;
  size_t aoff = 868352;                    // x_out (8*106*1024) first

  for(int l=0;l<12;l++){
    int n_attn = n;
    if(l>0){
      size_t tot = (size_t)NB*P*DM;
      dposadd<<<(int)((tot+255)/256),256,0,stream>>>(xc, pc, la, l, n, P);
    }
    int M = NB*n;
    // ---- attention ----
    dln<<<(M+63)/64,64,0,stream>>>(xc, ln1g + (size_t)l*DM, ln1b + (size_t)l*DM, Hb, M);
    dgemm<<<dim3(3072/16,(M+15)/16),256,0,stream>>>(Hb, wqkv + (size_t)l*3072*DM,
        nullptr, nullptr, QKV, M, 3072, DM, 0);
    drope<<<(NB*n*512+255)/256,256,0,stream>>>(QKV, freqs + (size_t)l*273*64, Qb, Kb, Vb, n);
    dscores<<<(NB*NH*n+63)/64,64,0,stream>>>(Qb, Kb, out + aoff, n);
    {
      size_t tot = (size_t)NB*NH*n*HD;
      dpv<<<(int)((tot+255)/256),256,0,stream>>>(out + aoff, Vb, Ob, n);
    }
    dgemm<<<dim3(DM/16,(M+15)/16),256,0,stream>>>(Ob, wout + (size_t)l*DM*DM,
        bout + (size_t)l*DM, xc, xa, M, DM, DM, 0);
    { float* t=xc; xc=xa; xa=t; }
    // ---- prune ----
    if(l==3 || l==6 || l==9){
      int k = (P*7 + 9)/10;                // ceil(P*0.7) = 180,126,89
      dhuman32<<<(NB*P+255)/256,256,0,stream>>>(out + aoff, HUM32, n);
      dselect32<<<1,64,0,stream>>>(HUM32, SEL, P, k);
      int n_new = JT + k;
      size_t tot = (size_t)NB*n_new*DM;
      dgather<<<(int)((tot+255)/256),256,0,stream>>>(xc, pc, SEL, xa, pa, n, k);
      { float* t=xc; xc=xa; xa=t; }
      { float* t=pc; pc=pa; pa=t; }
      n = n_new; P = k;
    }
    // ---- FFN ----
    int Mf = NB*n;
    dln<<<(Mf+63)/64,64,0,stream>>>(xc, ln2g + (size_t)l*DM, ln2b + (size_t)l*DM, Hb, Mf);
    dgemm<<<dim3(DMLP/16,(Mf+15)/16),256,0,stream>>>(Hb, w1 + (size_t)l*DMLP*DM,
        b1 + (size_t)l*DMLP, nullptr, FF, Mf, DMLP, DM, 1);
    dgemm<<<dim3(DM/16,(Mf+15)/16),256,0,stream>>>(FF, w2 + (size_t)l*DM*DMLP,
        b2 + (size_t)l*DM, xc, xa, Mf, DM, DMLP, 0);
    { float* t=xc; xc=xa; xa=t; }
    aoff += (size_t)128*n_attn*n_attn;
  }

  // final copies (f32): x_out, pos_out
  dcopy<<<(868352+255)/256,256,0,stream>>>(xc, out, 868352);
  dcopy<<<(729088+255)/256,256,0,stream>>>(pc, out + 64658688, 729088);
}

// Round 10
// 19080.571 us; speedup vs baseline: 2.6491x; 2.6491x over previous
//
#include <hip/hip_runtime.h>
#include <math.h>

#define NH 16
#define HD 64
#define DM 1024
#define DMLP 4096
#define NB 8
#define JT 17
#define LN_EPS 1e-5

__global__ __launch_bounds__(256) void sentinel_kernel(float* o, float v){
  o[threadIdx.x] = v;
}

// ---------------- wave helpers (f64) ----------------
__device__ __forceinline__ double wave_sum_d(double v){
  for(int o=32;o>0;o>>=1) v += __shfl_xor(v,o);
  return v;
}
__device__ __forceinline__ double wave_max_d(double v){
  for(int o=32;o>0;o>>=1) v = fmax(v, __shfl_xor(v,o));
  return v;
}

// ---------------- elementwise ----------------
__global__ __launch_bounds__(256) void dbcast(const float* __restrict__ src, float* __restrict__ dst){
  size_t id = (size_t)blockIdx.x*256 + threadIdx.x;
  if(id < (size_t)NB*256*DM) dst[id] = src[id % ((size_t)256*DM)];
}

__global__ __launch_bounds__(256) void dcopy(const float* __restrict__ src, float* __restrict__ dst, size_t n){
  size_t id = (size_t)blockIdx.x*256 + threadIdx.x;
  if(id < n) dst[id] = src[id];
}

// pos *= la[l]; x[:, JT+p, :] += pos   (f64 math, f32 store; bitwise same as before)
__global__ __launch_bounds__(256) void dposadd(float* __restrict__ x, float* __restrict__ pos,
    const float* __restrict__ la, int l, int n, int P){
  size_t id = (size_t)blockIdx.x*256 + threadIdx.x;
  size_t tot = (size_t)NB*P*DM;
  if(id >= tot) return;
  int c = (int)(id % DM); size_t rt = id / DM;
  int p = (int)(rt % P); int b = (int)(rt / P);
  double lav = (double)la[l];
  size_t pi = ((size_t)b*P + p)*DM + c;
  double pv = (double)pos[pi] * lav;
  pos[pi] = (float)pv;
  size_t xi = ((size_t)b*n + JT + p)*DM + c;
  x[xi] = (float)((double)x[xi] + pv);
}

// ---------------- LayerNorm: one BLOCK per row, f64 tree reductions ----------------
__global__ __launch_bounds__(256) void dln2(const float* __restrict__ x,
    const float* __restrict__ g, const float* __restrict__ bb, float* __restrict__ outp){
  __shared__ double red[8];
  size_t row = blockIdx.x;
  int tid = threadIdx.x;
  float4 v = ((const float4*)(x + row*DM))[tid];
  double s = (double)v.x + (double)v.y + (double)v.z + (double)v.w;
  s = wave_sum_d(s);
  if((tid&63)==0) red[tid>>6] = s;
  __syncthreads();
  double mean = (red[0]+red[1]+red[2]+red[3]) * (1.0/1024.0);
  double dx = (double)v.x-mean, dy = (double)v.y-mean, dz = (double)v.z-mean, dw = (double)v.w-mean;
  double sq = dx*dx+dy*dy+dz*dz+dw*dw;
  sq = wave_sum_d(sq);
  if((tid&63)==0) red[4+(tid>>6)] = sq;
  __syncthreads();
  double var = (red[4]+red[5]+red[6]+red[7]) * (1.0/1024.0);
  double inv = 1.0 / sqrt(var + LN_EPS);
  float4 gv = ((const float4*)g)[tid];
  float4 bv = ((const float4*)bb)[tid];
  float4 o;
  o.x = (float)(dx*inv*(double)gv.x + (double)bv.x);
  o.y = (float)(dy*inv*(double)gv.y + (double)bv.y);
  o.z = (float)(dz*inv*(double)gv.z + (double)bv.z);
  o.w = (float)(dw*inv*(double)gv.w + (double)bv.w);
  ((float4*)(outp + row*DM))[tid] = o;
}

// ---------------- f64-acc NT GEMM: 64x64 tile, 4x4 microtile, serial-k order ----------------
// C[M,N] = A[M,K]*Bw[N,K]^T (+bias)(+gelu)(+res). Per-output k-order identical to the
// old 16x16 dgemm (k ascending) => bitwise-identical results.
__global__ __launch_bounds__(256) void ggemm(const float* __restrict__ A, const float* __restrict__ Bw,
    const float* __restrict__ bias, const float* __restrict__ res,
    float* __restrict__ C, int M, int N, int K, int act){
  __shared__ float As[32][68];
  __shared__ float Bs[32][68];
  const int tid = threadIdx.x;
  const int tx = tid & 15, ty = tid >> 4;
  const int m0 = blockIdx.y * 64, n0 = blockIdx.x * 64;
  double acc[4][4] = {};
  for(int k0 = 0; k0 < K; k0 += 32){
    #pragma unroll
    for(int r=0;r<2;r++){
      int f = tid + r*256;
      int row = f >> 3;
      int kk = (f & 7) << 2;
      int gm = m0 + row;
      float4 av = make_float4(0.f,0.f,0.f,0.f);
      if(gm < M) av = *(const float4*)(A + (size_t)gm*K + k0 + kk);
      As[kk+0][row]=av.x; As[kk+1][row]=av.y; As[kk+2][row]=av.z; As[kk+3][row]=av.w;
      float4 bv = *(const float4*)(Bw + (size_t)(n0+row)*K + k0 + kk);
      Bs[kk+0][row]=bv.x; Bs[kk+1][row]=bv.y; Bs[kk+2][row]=bv.z; Bs[kk+3][row]=bv.w;
    }
    __syncthreads();
    #pragma unroll
    for(int kk=0;kk<32;kk++){
      float4 a4 = *(const float4*)&As[kk][ty<<2];
      float4 b4 = *(const float4*)&Bs[kk][tx<<2];
      double a0=a4.x, a1=a4.y, a2=a4.z, a3=a4.w;
      double b0=b4.x, b1=b4.y, b2=b4.z, b3=b4.w;
      acc[0][0]+=a0*b0; acc[0][1]+=a0*b1; acc[0][2]+=a0*b2; acc[0][3]+=a0*b3;
      acc[1][0]+=a1*b0; acc[1][1]+=a1*b1; acc[1][2]+=a1*b2; acc[1][3]+=a1*b3;
      acc[2][0]+=a2*b0; acc[2][1]+=a2*b1; acc[2][2]+=a2*b2; acc[2][3]+=a2*b3;
      acc[3][0]+=a3*b0; acc[3][1]+=a3*b1; acc[3][2]+=a3*b2; acc[3][3]+=a3*b3;
    }
    __syncthreads();
  }
  #pragma unroll
  for(int i=0;i<4;i++){
    int gm = m0 + (ty<<2) + i;
    if(gm >= M) continue;
    int gn = n0 + (tx<<2);
    #pragma unroll
    for(int j=0;j<4;j++){
      double c = acc[i][j];
      if(bias) c += (double)bias[gn+j];
      if(act)  c = 0.5*c*(1.0 + erf(c*0.70710678118654752440));
      if(res)  c += (double)res[(size_t)gm*N + gn + j];
      C[(size_t)gm*N + gn + j] = (float)c;
    }
  }
}

// ---------------- RoPE: Q(B,H,n,64)*SCALE, K^T(B,H,64,n), V(B,H,n,64) ----------------
__global__ __launch_bounds__(256) void drope(const float* __restrict__ qkv, const float* __restrict__ fc,
    float* __restrict__ Q, float* __restrict__ KT, float* __restrict__ V, int n){
  int id = blockIdx.x*256 + threadIdx.x;     // NB*n*512
  if(id >= NB*n*512) return;
  int pr = id & 511; int bt = id >> 9;
  int b = bt / n, t = bt % n;
  int h = pr >> 5, d2 = pr & 31;
  const float* row = qkv + (size_t)bt*3072;
  double c = (double)fc[(t*32+d2)*2], s = (double)fc[(t*32+d2)*2+1];
  double qa = (double)row[h*HD+2*d2], qb = (double)row[h*HD+2*d2+1];
  double ka = (double)row[DM + h*HD+2*d2], kb = (double)row[DM + h*HD+2*d2+1];
  size_t qoff = ((size_t)(b*NH+h)*n + t)*HD + 2*d2;
  Q[qoff]   = (float)((qa*c - qb*s)*0.03125);
  Q[qoff+1] = (float)((qa*s + qb*c)*0.03125);
  size_t koff = ((size_t)(b*NH+h)*HD + 2*d2)*n + t;
  KT[koff]     = (float)(ka*c - kb*s);
  KT[koff + n] = (float)(ka*s + kb*c);
  size_t voff = ((size_t)(b*NH+h)*n + t)*HD + 2*d2;
  V[voff]   = row[2048 + h*HD + 2*d2];
  V[voff+1] = row[2048 + h*HD + 2*d2 + 1];
}

// ---------------- scores+softmax: one WAVE per (b,h,i); serial-d dots (bitwise-same) ----------------
__global__ __launch_bounds__(256) void ascore(const float* __restrict__ Q, const float* __restrict__ KT,
    float* __restrict__ attn, int n){
  int lane = threadIdx.x & 63, wv = threadIdx.x >> 6;
  int bh = blockIdx.x;
  int i = blockIdx.y*4 + wv;
  if(i >= n) return;
  float qv = Q[((size_t)bh*n + i)*HD + lane];
  const float* kb = KT + (size_t)bh*HD*n;
  double acc[5] = {0.0,0.0,0.0,0.0,0.0};
  for(int d=0; d<HD; d++){
    double qd = (double)__shfl(qv, d);
    const float* kr = kb + (size_t)d*n;
    #pragma unroll
    for(int c=0;c<5;c++){
      int j = c*64 + lane;
      acc[c] += qd * (double)(j < n ? kr[j] : 0.f);
    }
  }
  double mx = -1.0e300;
  #pragma unroll
  for(int c=0;c<5;c++) if(c*64+lane < n) mx = fmax(mx, acc[c]);
  mx = wave_max_d(mx);
  double e[5]; double sum = 0.0;
  #pragma unroll
  for(int c=0;c<5;c++){
    e[c] = (c*64+lane < n) ? exp(acc[c]-mx) : 0.0;
    sum += e[c];
  }
  sum = wave_sum_d(sum);
  double inv = 1.0/sum;
  float* arow = attn + ((size_t)bh*n + i)*n;
  #pragma unroll
  for(int c=0;c<5;c++){
    int j = c*64 + lane;
    if(j < n) arow[j] = (float)(e[c]*inv);
  }
}

// ---------------- PV: one WAVE per (b,h,i), lane = d; serial-j (bitwise-same as dpv) ----------------
__global__ __launch_bounds__(256) void apv(const float* __restrict__ attn, const float* __restrict__ V,
    float* __restrict__ O, int n){
  int lane = threadIdx.x & 63, wv = threadIdx.x >> 6;
  int bh = blockIdx.x;
  int i = blockIdx.y*4 + wv;
  if(i >= n) return;
  int b = bh >> 4, h = bh & 15;
  const float* ar = attn + ((size_t)bh*n + i)*n;
  const float* vb = V + (size_t)bh*n*HD + lane;
  double acc = 0.0;
  for(int j=0;j<n;j++)
    acc += (double)ar[j] * (double)vb[(size_t)j*HD];
  O[((size_t)(b*n + i))*DM + h*HD + lane] = (float)acc;
}

// ---------------- human scores: f32 from STORED attn, np reduction order (UNCHANGED) ----------------
__global__ __launch_bounds__(256) void dhuman32(const float* __restrict__ attn, float* __restrict__ hum32, int n){
  int id = blockIdx.x*256 + threadIdx.x;
  int P = n - JT;
  if(id >= NB*P) return;
  int b = id / P, p = id % P;
  float s = 0.f;
  for(int i=0;i<JT;i++){
    float th = 0.f;
    for(int h=0;h<NH;h++) th += attn[(((size_t)(b*NH+h))*n + i)*n + JT + p];
    th *= 0.0625f;
    s += th;
  }
  hum32[b*256 + p] = s;
}

// ---------------- top-k: parallel rank-counting; identical semantics to selection sort ----------------
// rank(p) = #{q : h[q] > h[p]  or (h[q]==h[p] and q<p)};  sel[rank]=p for rank<k
__global__ __launch_bounds__(256) void dselect_par(const float* __restrict__ hum, int* __restrict__ sel,
    int P, int k){
  __shared__ float v[256];
  int b = blockIdx.x, p = threadIdx.x;
  v[p] = (p < P) ? hum[b*256 + p] : -3.0e38f;
  __syncthreads();
  if(p < P){
    float mv = v[p];
    int rank = 0;
    for(int q=0;q<256;q++){
      float vq = v[q];
      rank += (vq > mv) || (vq == mv && q < p);
    }
    if(rank < k) sel[b*192 + rank] = p;
  }
}

// ---------------- gather ----------------
__global__ __launch_bounds__(256) void dgather(const float* __restrict__ xin, const float* __restrict__ pin,
    const int* __restrict__ sel, float* __restrict__ xout, float* __restrict__ pout, int n_old, int k){
  int n_new = JT + k;
  size_t id = (size_t)blockIdx.x*256 + threadIdx.x;
  size_t tot = (size_t)NB*n_new*DM;
  if(id >= tot) return;
  int c = (int)(id % DM); size_t rt = id / DM;
  int t = (int)(rt % n_new); int b = (int)(rt / n_new);
  int src = (t < JT) ? t : (JT + sel[b*192 + (t-JT)]);
  xout[((size_t)b*n_new + t)*DM + c] = xin[((size_t)b*n_old + src)*DM + c];
  if(t >= JT)
    pout[((size_t)b*k + (t-JT))*DM + c] = pin[((size_t)b*(n_old-JT) + (src-JT))*DM + c];
}

// ---------------- host ----------------
extern "C" void kernel_launch(void* const* d_in, const int* in_sizes, int n_in,
                              void* d_out, int out_size, void* d_ws, size_t ws_size,
                              hipStream_t stream){
  float* out = (float*)d_out;

  const size_t NEED = 26560512ull * 4ull;    // 106.2 MB
  if(ws_size < NEED){
    sentinel_kernel<<<1,256,0,stream>>>(out, 1000000.0f);
    return;
  }

  const float* x_in  = (const float*)d_in[0];
  const float* freqs = (const float*)d_in[1];
  const float* la    = (const float*)d_in[2];
  const float* pos_in= (const float*)d_in[3];
  const float* ln1g  = (const float*)d_in[4];
  const float* ln1b  = (const float*)d_in[5];
  const float* wqkv  = (const float*)d_in[6];
  const float* wout  = (const float*)d_in[7];
  const float* bout  = (const float*)d_in[8];
  const float* ln2g  = (const float*)d_in[9];
  const float* ln2b  = (const float*)d_in[10];
  const float* w1    = (const float*)d_in[11];
  const float* b1    = (const float*)d_in[12];
  const float* w2    = (const float*)d_in[13];
  const float* b2    = (const float*)d_in[14];

  float* w = (float*)d_ws;
  float* XA = w;  w += 2236416;            // 8*273*1024
  float* XB = w;  w += 2236416;
  float* Hb = w;  w += 2236416;
  float* QKV= w;                            // 8*273*3072; FF spans QKV+Qb (dead in FFN phase)
  float* FF = QKV;
  float* HUM32 = QKV;                       // alias: live only during prune (QKV dead there)
                  w += 6709248;
  float* Qb = w;  w += 2236416;
  float* Kb = w;  w += 2236416;            // K^T layout (B,H,64,n)
  float* Vb = w;  w += 2236416;
  float* Ob = w;  w += 2236416;
  float* PA = w;  w += 2097152;            // 8*256*1024
  float* PB = w;  w += 2097152;
  int*   SEL = (int*)w; w += 2048;         // stride 192 per batch

  hipMemcpyAsync(XA, x_in, (size_t)NB*273*DM*sizeof(float), hipMemcpyDeviceToDevice, stream);
  dbcast<<<8192,256,0,stream>>>(pos_in, PA);

  float* xc = XA; float* xa = XB;
  float* pc = PA; float* pa = PB;
  int n = 273, P = 256;
  size_t aoff = 868352;                    // x_out (8*106*1024) first

  for(int l=0;l<12;l++){
    int n_attn = n;
    if(l>0){
      size_t tot = (size_t)NB*P*DM;
      dposadd<<<(int)((tot+255)/256),256,0,stream>>>(xc, pc, la, l, n, P);
    }
    int M = NB*n;
    // ---- attention ----
    dln2<<<M,256,0,stream>>>(xc, ln1g + (size_t)l*DM, ln1b + (size_t)l*DM, Hb);
    ggemm<<<dim3(3072/64,(M+63)/64),256,0,stream>>>(Hb, wqkv + (size_t)l*3072*DM,
        nullptr, nullptr, QKV, M, 3072, DM, 0);
    drope<<<(NB*n*512+255)/256,256,0,stream>>>(QKV, freqs + (size_t)l*273*64, Qb, Kb, Vb, n);
    ascore<<<dim3(NB*NH,(n+3)/4),256,0,stream>>>(Qb, Kb, out + aoff, n);
    apv<<<dim3(NB*NH,(n+3)/4),256,0,stream>>>(out + aoff, Vb, Ob, n);
    ggemm<<<dim3(DM/64,(M+63)/64),256,0,stream>>>(Ob, wout + (size_t)l*DM*DM,
        bout + (size_t)l*DM, xc, xa, M, DM, DM, 0);
    { float* t=xc; xc=xa; xa=t; }
    // ---- prune ----
    if(l==3 || l==6 || l==9){
      int k = (P*7 + 9)/10;                // ceil(P*0.7) = 180,126,89
      dhuman32<<<(NB*P+255)/256,256,0,stream>>>(out + aoff, HUM32, n);
      dselect_par<<<NB,256,0,stream>>>(HUM32, SEL, P, k);
      int n_new = JT + k;
      size_t tot = (size_t)NB*n_new*DM;
      dgather<<<(int)((tot+255)/256),256,0,stream>>>(xc, pc, SEL, xa, pa, n, k);
      { float* t=xc; xc=xa; xa=t; }
      { float* t=pc; pc=pa; pa=t; }
      n = n_new; P = k;
    }
    // ---- FFN ----
    int Mf = NB*n;
    dln2<<<Mf,256,0,stream>>>(xc, ln2g + (size_t)l*DM, ln2b + (size_t)l*DM, Hb);
    ggemm<<<dim3(DMLP/64,(Mf+63)/64),256,0,stream>>>(Hb, w1 + (size_t)l*DMLP*DM,
        b1 + (size_t)l*DMLP, nullptr, FF, Mf, DMLP, DM, 1);
    ggemm<<<dim3(DM/64,(Mf+63)/64),256,0,stream>>>(FF, w2 + (size_t)l*DM*DMLP,
        b2 + (size_t)l*DM, xc, xa, Mf, DM, DMLP, 0);
    { float* t=xc; xc=xa; xa=t; }
    aoff += (size_t)128*n_attn*n_attn;
  }

  // final copies (f32): x_out, pos_out
  dcopy<<<(868352+255)/256,256,0,stream>>>(xc, out, 868352);
  dcopy<<<(729088+255)/256,256,0,stream>>>(pc, out + 64658688, 729088);
}